// Round 12
// baseline (191.350 us; speedup 1.0000x reference)
//
#include <hip/hip_runtime.h>
#include <hip/hip_bf16.h>
#include <math.h>

typedef __attribute__((ext_vector_type(4))) float f32x4;
typedef __attribute__((ext_vector_type(8))) int i32x8;

#define HW 262144        // 512*512
#define M_SP 1089        // 33*33

// ---- ws layout in 4-byte words (all regions fully rewritten every call; no cross-call state) ----
#define OFF_PART  0                        // u32[16][16][4096] = 1048576
#define OFF_BSUM  1048576                  // u32[16][16]       = 256
#define OFF_CNT1P 1048832                  // u32[16][16][8]    = 2048
#define OFF_W2R   1050880                  // fp8[9][1024][128] = 294912 words
#define OFF_ZT    1345792                  // fp8[16][37][35][128] = 663040 words
#define OFF_FEATP 2008832                  // f32[9][16][1024]  = 147456 words

__device__ inline unsigned wred_u32(unsigned v) {
#pragma unroll
    for (int off = 32; off > 0; off >>= 1) v += __shfl_down(v, off);
    return v;
}

// float -> OCP fp8 e4m3 (RNE)
__device__ inline unsigned char f2e4m3(float x) {
    unsigned s = (__float_as_uint(x) >> 31) << 7;
    float a = fabsf(x);
    if (a >= 464.f) return (unsigned char)(s | 0x7E);
    if (a < 0.0009765625f) return (unsigned char)s;
    int e; float m = frexpf(a, &e); (void)m;
    int E = e + 6;
    if (E >= 1) {
        float f = ldexpf(a, -(e - 1));
        int q = (int)rintf((f - 1.f) * 8.f);
        if (q == 8) { q = 0; ++E; }
        if (E >= 16) return (unsigned char)(s | 0x7E);
        return (unsigned char)(s | (E << 3) | q);
    } else {
        int q = (int)rintf(ldexpf(a, 9));
        if (q >= 8) return (unsigned char)(s | 0x08);
        return (unsigned char)(s | q);
    }
}

// ---------------- fused prep: hist (blocks 0..255) + w2->fp8 (blocks 256..511) ----------
__global__ __launch_bounds__(512) void prep_kernel(const float* __restrict__ x1,
                                                   const float* __restrict__ w2,
                                                   unsigned* __restrict__ part,
                                                   unsigned* __restrict__ bsum,
                                                   unsigned* __restrict__ cnt1p,
                                                   unsigned char* __restrict__ w2r) {
    const int bid = blockIdx.x;
    const int tid = threadIdx.x;

    if (bid >= 256) {
        const int oc = (bid - 256) * 4 + (tid >> 7);
        const int ic = tid & 127;
        const float* src = w2 + oc * 1152 + ic * 9;
        float t[9];
#pragma unroll
        for (int k = 0; k < 9; ++k) t[k] = src[k];
#pragma unroll
        for (int k = 0; k < 9; ++k)
            w2r[(k << 17) + (oc << 7) + ic] = f2e4m3(t[k]);
        return;
    }

    const int b = bid >> 4, chunk = bid & 15;
    __shared__ unsigned h2[4096];
    __shared__ unsigned wv[8][8];
    __shared__ unsigned rsum[512];
    for (int i = tid; i < 4096; i += 512) h2[i] = 0u;
    __syncthreads();

    const float4* L4 = (const float4*)(x1 + (size_t)b * 3 * HW);
    const float4* A4 = L4 + 65536;
    const float4* B4 = L4 + 131072;
    const int start = chunk * 4096;

    unsigned long long cL = 0ull;
#pragma unroll 1
    for (int it = 0; it < 8; it += 4) {
        float4 lb[4], ab[4], bbv[4];
#pragma unroll
        for (int u = 0; u < 4; ++u) {
            int idx = start + (it + u) * 512 + tid;
            lb[u] = L4[idx]; ab[u] = A4[idx]; bbv[u] = B4[idx];
        }
#pragma unroll
        for (int u = 0; u < 4; ++u) {
            const float lv[4] = {lb[u].x, lb[u].y, lb[u].z, lb[u].w};
            const float av[4] = {ab[u].x, ab[u].y, ab[u].z, ab[u].w};
            const float bv[4] = {bbv[u].x, bbv[u].y, bbv[u].z, bbv[u].w};
#pragma unroll
            for (int e = 0; e < 4; ++e) {
                float l = lv[e], a = av[e], bb = bv[e];
                float va = (a + 1.f) * 0.5f;
                float vb = (bb + 1.f) * 0.5f;
                if (a != 0.f && bb != 0.f && va >= 0.f && va <= 1.f && vb >= 0.f && vb <= 1.f) {
                    int ia = min(max((int)floorf(va * 64.f), 0), 63);
                    int ib = min(max((int)floorf(vb * 64.f), 0), 63);
                    atomicAdd(&h2[ia * 64 + ib], 1u);
                }
                float vl = (l + 1.f) * 0.5f;
                if (l != 0.f && vl >= 0.f && vl <= 1.f) {
                    int il = min(max((int)floorf(vl * 8.f), 0), 7);
                    cL += 1ull << (il << 3);
                }
            }
        }
    }
    unsigned cc[8];
#pragma unroll
    for (int e = 0; e < 8; ++e) cc[e] = (unsigned)((cL >> (e << 3)) & 0xffull);
#pragma unroll
    for (int e = 0; e < 8; ++e) cc[e] = wred_u32(cc[e]);
    if ((tid & 63) == 0) {
        int w = tid >> 6;
#pragma unroll
        for (int e = 0; e < 8; ++e) wv[w][e] = cc[e];
    }
    __syncthreads();
    if (tid < 8) {
        unsigned s = 0;
#pragma unroll
        for (int w = 0; w < 8; ++w) s += wv[w][tid];
        cnt1p[((size_t)b * 16 + chunk) * 8 + tid] = s;
    }
    // partial writeout + block-sum (non-atomic, idempotent)
    uint4* pd = (uint4*)(part + (((size_t)b * 16 + chunk) << 12));
    const uint4* hs = (const uint4*)h2;
    unsigned mysum = 0;
    for (int i = tid; i < 1024; i += 512) {
        uint4 v = hs[i];
        pd[i] = v;
        mysum += v.x + v.y + v.z + v.w;
    }
    rsum[tid] = mysum;
    __syncthreads();
    for (int off = 256; off > 0; off >>= 1) {
        if (tid < off) rsum[tid] += rsum[tid + off];
        __syncthreads();
    }
    if (tid == 0) bsum[b * 16 + chunk] = rsum[0];
}

// ---------------- conv1 (+inline hist normalize) -> zt[b][37][35][128] fp8 (+halo zero) ------
__global__ __launch_bounds__(256) void conv1_pool(
    const unsigned* __restrict__ part, const unsigned* __restrict__ bsum,
    const unsigned* __restrict__ cnt1p,
    const float* __restrict__ w1, const float* __restrict__ g1,
    const float* __restrict__ b1v, const float* __restrict__ m1,
    const float* __restrict__ v1, unsigned char* __restrict__ zt)
{
    const int p = blockIdx.x;   // 0..32
    const int b = blockIdx.y;
    __shared__ float aL[128], cL[128], sL[128];
    __shared__ float Hrow[3][64];          // raw counts; scaled by inv2 at use
    __shared__ unsigned bs16[16];
    __shared__ float hlsh[8];
    __shared__ float qmx[33], qmn[33];
    __shared__ int qbd[33];
    const int tid = threadIdx.x;

    // phase 1: gather counts
    if (tid < 192) {
        int rr = tid >> 6, cc = tid & 63;
        int row = 2 * p - 2 + rr;
        float s = 0.f;
        if (row >= 0 && row < 64) {
            unsigned acc = 0;
#pragma unroll 1
            for (int k = 0; k < 16; ++k)
                acc += part[(((size_t)b * 16 + k) << 12) + (cc << 6) + row];  // bin = ia*64+ib, ia=cc, ib=row
            s = (float)acc;
        }
        Hrow[rr][cc] = s;
    } else if (tid < 208) {
        bs16[tid - 192] = bsum[b * 16 + (tid - 192)];
    } else if (tid < 216) {
        int c = tid - 208;
        unsigned s = 0;
#pragma unroll 1
        for (int k = 0; k < 16; ++k) s += cnt1p[((size_t)b * 16 + k) * 8 + c];
        hlsh[c] = (float)s;
    }
    __syncthreads();

    unsigned tt = 0;
#pragma unroll
    for (int i = 0; i < 16; ++i) tt += bs16[i];
    const float inv2 = 1.f / (float)tt;
    float hltot = 0.f;
#pragma unroll
    for (int c = 0; c < 8; ++c) hltot += hlsh[c];
    const float invl = 1.f / hltot;

    if (tid < 128) {
        int oc = tid;
        float inv = g1[oc] * rsqrtf(v1[oc] + 1e-5f);
        float s = b1v[oc] - m1[oc] * inv;
        float Kc = 0.f;
#pragma unroll
        for (int c = 1; c < 9; ++c) Kc = fmaf(w1[oc * 9 + c], hlsh[c - 1] * invl, Kc);
        aL[oc] = w1[oc * 9] * inv;
        cL[oc] = fmaf(Kc, inv, s);
        sL[oc] = s;
    }
    if (tid >= 128 && tid < 161) {
        int q = tid - 128;
        float mx = -1e30f, mn = 1e30f;
        int bd = 0;
#pragma unroll
        for (int dy = 0; dy < 3; ++dy) {
            int yi = 2 * p - 1 + dy;
            if (yi < 0 || yi > 65) continue;
#pragma unroll
            for (int dx = 0; dx < 3; ++dx) {
                int yj = 2 * q - 1 + dx;
                if (yj < 0 || yj > 65) continue;
                if (yi == 0 || yi == 65 || yj == 0 || yj == 65) bd = 1;
                else {
                    float h = Hrow[dy][2 * q - 2 + dx];
                    mx = fmaxf(mx, h); mn = fminf(mn, h);
                }
            }
        }
        qmx[q] = mx * inv2; qmn[q] = mn * inv2; qbd[q] = bd;
    }
    __syncthreads();
    unsigned char* zrow = zt + (((size_t)b * 37 + (p + 1)) * 35 + 1) * 128;
    for (int it = tid; it < 33 * 128; it += 256) {
        int q = it >> 7, oc = it & 127;
        float a = aL[oc];
        float v = fmaf(a, (a > 0.f ? qmx[q] : qmn[q]), cL[oc]);
        if (qbd[q]) v = fmaxf(v, sL[oc]);
        v = fmaxf(v, 0.f);
        zrow[q * 128 + oc] = f2e4m3(v);
    }
    // halo zeroing
    {
        int col = (tid < 128) ? 0 : 34;
        int ch = tid & 127;
        zt[(((size_t)b * 37 + (p + 1)) * 35 + col) * 128 + ch] = 0;
    }
    if (p < 4) {
        int hr = (p == 0) ? 0 : (33 + p);
        unsigned char* hrow = zt + ((size_t)b * 37 + hr) * 35 * 128;
        for (int i = tid; i < 35 * 128; i += 256) hrow[i] = 0;
    }
}

// ---------------- conv2: 9 tap-GEMMs, MX-fp8 K=128, single 32KB buffer, 5 blocks/CU ----------
__global__ __launch_bounds__(256, 5) void conv2_mfma(
        const unsigned char* __restrict__ zt,
        const unsigned char* __restrict__ w2r,
        const float* __restrict__ g2, const float* __restrict__ b2v,
        const float* __restrict__ m2, const float* __restrict__ v2,
        float* __restrict__ featp)
{
    __shared__ char lds[32768];   // A 16KB + B 16KB (single buffer; TLP hides staging)
    const int tid = threadIdx.x;
    const int lane = tid & 63, wid = tid >> 6;
    const int b = blockIdx.z;
    const int nbase = blockIdx.x * 128;
    const int mbase = blockIdx.y * 128;
    const int lr16 = lane & 15, lk = lane >> 4;
    const int wm = (wid >> 1) * 64, wn = (wid & 1) * 64;

    const int csrc = ((lane & 7) ^ (lane >> 3)) << 4;
    const unsigned char* aS[4];
    const unsigned char* bS[4];
    {
        const unsigned char* ztb = zt + (size_t)b * 165760;   // 37*35*128
#pragma unroll
        for (int v = 0; v < 4; ++v) {
            int R = wid * 32 + v * 8 + (lane >> 3);
            int m = mbase + R;
            int p = m / 33, q = m - p * 33;
            aS[v] = ztb + (p * 35 + q) * 128 + csrc;
            bS[v] = w2r + (size_t)(nbase + R) * 128 + csrc;
        }
    }

    f32x4 acc[4][4];
#pragma unroll
    for (int i = 0; i < 4; ++i)
#pragma unroll
        for (int j = 0; j < 4; ++j) acc[i][j] = (f32x4){0.f, 0.f, 0.f, 0.f};

    auto stage = [&](int tap) {
        const int kh = tap / 3, kw = tap - kh * 3;
        const int aoff = (kh * 35 + kw) * 128;
        const int boff = tap * 131072;
        char* ab = lds + wid * 4096;
        char* bb = lds + 16384 + wid * 4096;
#pragma unroll
        for (int v = 0; v < 4; ++v)
            __builtin_amdgcn_global_load_lds(
                (const __attribute__((address_space(1))) unsigned int*)(aS[v] + aoff),
                (__attribute__((address_space(3))) unsigned int*)(ab + v * 1024), 16, 0, 0);
#pragma unroll
        for (int v = 0; v < 4; ++v)
            __builtin_amdgcn_global_load_lds(
                (const __attribute__((address_space(1))) unsigned int*)(bS[v] + boff),
                (__attribute__((address_space(3))) unsigned int*)(bb + v * 1024), 16, 0, 0);
    };

    auto compute = [&]() {
        const char* Ab = lds;
        const char* Bb = lds + 16384;
        i32x8 af[4], bf[4];
#pragma unroll
        for (int i = 0; i < 4; ++i) {
            int row = wm + i * 16 + lr16;
            const char* base = Ab + row * 128;
            int x = row & 7;
            int4 lo = *(const int4*)(base + (((2 * lk) ^ x) << 4));
            int4 hi = *(const int4*)(base + (((2 * lk + 1) ^ x) << 4));
            af[i] = (i32x8){lo.x, lo.y, lo.z, lo.w, hi.x, hi.y, hi.z, hi.w};
        }
#pragma unroll
        for (int j = 0; j < 4; ++j) {
            int row = wn + j * 16 + lr16;
            const char* base = Bb + row * 128;
            int x = row & 7;
            int4 lo = *(const int4*)(base + (((2 * lk) ^ x) << 4));
            int4 hi = *(const int4*)(base + (((2 * lk + 1) ^ x) << 4));
            bf[j] = (i32x8){lo.x, lo.y, lo.z, lo.w, hi.x, hi.y, hi.z, hi.w};
        }
#pragma unroll
        for (int i = 0; i < 4; ++i)
#pragma unroll
            for (int j = 0; j < 4; ++j)
                acc[i][j] = __builtin_amdgcn_mfma_scale_f32_16x16x128_f8f6f4(
                    af[i], bf[j], acc[i][j],
                    0, 0, 0, 0x7F7F7F7F, 0, 0x7F7F7F7F);
    };

#pragma unroll 1
    for (int t = 0; t < 9; ++t) {
        stage(t);
        asm volatile("s_waitcnt vmcnt(0)" ::: "memory");
        __syncthreads();
        compute();
        __syncthreads();
    }

    // epilogue: BN2 + ReLU + masked column sums -> featp
    float* red = (float*)lds;
#pragma unroll
    for (int j = 0; j < 4; ++j) {
        int nl = wn + j * 16 + lr16;
        int n = nbase + nl;
        float inv = g2[n] * rsqrtf(v2[n] + 1e-5f);
        float sh = b2v[n] - m2[n] * inv;
        float ssum = 0.f;
#pragma unroll
        for (int i = 0; i < 4; ++i) {
            int mlb = wm + i * 16 + lk * 4;
#pragma unroll
            for (int r = 0; r < 4; ++r) {
                if (mbase + mlb + r < M_SP)
                    ssum += fmaxf(fmaf(acc[i][j][r], inv, sh), 0.f);
            }
        }
        red[((wid >> 1) * 4 + lk) * 128 + nl] = ssum;
    }
    __syncthreads();
    if (tid < 128) {
        float s = 0.f;
#pragma unroll
        for (int c = 0; c < 8; ++c) s += red[c * 128 + tid];
        featp[blockIdx.y * 16384 + b * 1024 + nbase + tid] = s * (1.f / 1089.f);
    }
}

// ---------------- head: fused x-copy + feature-sum + linear ----------------
__global__ __launch_bounds__(256) void linear_head(const float* __restrict__ featp,
                                                   const float* __restrict__ x,
                                                   const float* __restrict__ wl,
                                                   const float* __restrict__ bl,
                                                   float* __restrict__ out) {
    int jg = blockIdx.x, b = blockIdx.y;   // grid (16,16)
    __shared__ float fsum[1024];
    int tid = threadIdx.x;
    if (tid < 128)
        out[b * 2304 + jg * 128 + tid] = x[b * 2048 + jg * 128 + tid];
    for (int c = tid; c < 1024; c += 256) {
        float s = 0.f;
#pragma unroll
        for (int mb = 0; mb < 9; ++mb) s += featp[mb * 16384 + b * 1024 + c];
        fsum[c] = s;
    }
    __syncthreads();
    int w = tid >> 6, lane = tid & 63;
#pragma unroll
    for (int jj = 0; jj < 4; ++jj) {
        int j = jg * 16 + w * 4 + jj;
        const float* wr = wl + j * 1024;
        float s = 0.f;
        for (int k = lane; k < 1024; k += 64) s = fmaf(fsum[k], wr[k], s);
#pragma unroll
        for (int off = 32; off > 0; off >>= 1) s += __shfl_down(s, off);
        if (lane == 0) out[b * 2304 + 2048 + j] = s + bl[j];
    }
}

extern "C" void kernel_launch(void* const* d_in, const int* in_sizes, int n_in,
                              void* d_out, int out_size, void* d_ws, size_t ws_size,
                              hipStream_t stream) {
    const float* x  = (const float*)d_in[0];
    const float* x1 = (const float*)d_in[1];
    const float* w1 = (const float*)d_in[2];
    const float* g1 = (const float*)d_in[3];
    const float* b1 = (const float*)d_in[4];
    const float* m1 = (const float*)d_in[5];
    const float* v1 = (const float*)d_in[6];
    const float* w2 = (const float*)d_in[7];
    const float* g2 = (const float*)d_in[8];
    const float* b2 = (const float*)d_in[9];
    const float* m2 = (const float*)d_in[10];
    const float* v2 = (const float*)d_in[11];
    const float* wl = (const float*)d_in[12];
    const float* bl = (const float*)d_in[13];
    float* out = (float*)d_out;

    float* wsf = (float*)d_ws;
    unsigned* part  = (unsigned*)(wsf + OFF_PART);
    unsigned* bsum  = (unsigned*)(wsf + OFF_BSUM);
    unsigned* cnt1p = (unsigned*)(wsf + OFF_CNT1P);
    unsigned char* w2r = (unsigned char*)(wsf + OFF_W2R);
    unsigned char* zt  = (unsigned char*)(wsf + OFF_ZT);
    float* featp = wsf + OFF_FEATP;

    prep_kernel<<<512, 512, 0, stream>>>(x1, w2, part, bsum, cnt1p, w2r);
    conv1_pool<<<dim3(33, 16), 256, 0, stream>>>(part, bsum, cnt1p, w1, g1, b1, m1, v1, zt);
    conv2_mfma<<<dim3(8, 9, 16), 256, 0, stream>>>(zt, w2r, g2, b2, m2, v2, featp);
    linear_head<<<dim3(16, 16), 256, 0, stream>>>(featp, x, wl, bl, out);
}

// Round 13
// 75.564 us; speedup vs baseline: 2.5323x; 2.5323x over previous
//
#include <hip/hip_runtime.h>
#include <hip/hip_bf16.h>
#include <math.h>

typedef __attribute__((ext_vector_type(4))) float f32x4;
typedef __attribute__((ext_vector_type(8))) int i32x8;

#define HW 262144        // 512*512
#define M_SP 1089        // 33*33

// ---- ws layout in 4-byte words (all regions fully rewritten every call; no cross-call state) ----
#define OFF_PART  0                        // u32[16][16][4096] = 1048576
#define OFF_BSUM  1048576                  // u32[16][16]       = 256
#define OFF_CNT1P 1048832                  // u32[16][16][8]    = 2048
#define OFF_W2R   1050880                  // fp8[9][1024][128] = 294912 words
#define OFF_ZT    1345792                  // fp8[16][37][35][128] = 663040 words
#define OFF_FEATP 2008832                  // f32[9][16][1024]  = 147456 words

__device__ inline unsigned wred_u32(unsigned v) {
#pragma unroll
    for (int off = 32; off > 0; off >>= 1) v += __shfl_down(v, off);
    return v;
}

// float -> OCP fp8 e4m3 (RNE)
__device__ inline unsigned char f2e4m3(float x) {
    unsigned s = (__float_as_uint(x) >> 31) << 7;
    float a = fabsf(x);
    if (a >= 464.f) return (unsigned char)(s | 0x7E);
    if (a < 0.0009765625f) return (unsigned char)s;
    int e; float m = frexpf(a, &e); (void)m;
    int E = e + 6;
    if (E >= 1) {
        float f = ldexpf(a, -(e - 1));
        int q = (int)rintf((f - 1.f) * 8.f);
        if (q == 8) { q = 0; ++E; }
        if (E >= 16) return (unsigned char)(s | 0x7E);
        return (unsigned char)(s | (E << 3) | q);
    } else {
        int q = (int)rintf(ldexpf(a, 9));
        if (q >= 8) return (unsigned char)(s | 0x08);
        return (unsigned char)(s | q);
    }
}

// ---------------- fused prep: hist (blocks 0..255) + w2->fp8 (blocks 256..511) ----------
__global__ __launch_bounds__(512) void prep_kernel(const float* __restrict__ x1,
                                                   const float* __restrict__ w2,
                                                   unsigned* __restrict__ part,
                                                   unsigned* __restrict__ bsum,
                                                   unsigned* __restrict__ cnt1p,
                                                   unsigned char* __restrict__ w2r) {
    const int bid = blockIdx.x;
    const int tid = threadIdx.x;

    if (bid >= 256) {
        const int oc = (bid - 256) * 4 + (tid >> 7);
        const int ic = tid & 127;
        const float* src = w2 + oc * 1152 + ic * 9;
        float t[9];
#pragma unroll
        for (int k = 0; k < 9; ++k) t[k] = src[k];
#pragma unroll
        for (int k = 0; k < 9; ++k)
            w2r[(k << 17) + (oc << 7) + ic] = f2e4m3(t[k]);
        return;
    }

    const int b = bid >> 4, chunk = bid & 15;
    __shared__ unsigned h2[4096];
    __shared__ unsigned wv[8][8];
    __shared__ unsigned rsum[512];
    for (int i = tid; i < 4096; i += 512) h2[i] = 0u;
    __syncthreads();

    const float4* L4 = (const float4*)(x1 + (size_t)b * 3 * HW);
    const float4* A4 = L4 + 65536;
    const float4* B4 = L4 + 131072;
    const int start = chunk * 4096;

    unsigned long long cL = 0ull;
#pragma unroll 1
    for (int it = 0; it < 8; it += 4) {
        float4 lb[4], ab[4], bbv[4];
#pragma unroll
        for (int u = 0; u < 4; ++u) {
            int idx = start + (it + u) * 512 + tid;
            lb[u] = L4[idx]; ab[u] = A4[idx]; bbv[u] = B4[idx];
        }
#pragma unroll
        for (int u = 0; u < 4; ++u) {
            const float lv[4] = {lb[u].x, lb[u].y, lb[u].z, lb[u].w};
            const float av[4] = {ab[u].x, ab[u].y, ab[u].z, ab[u].w};
            const float bv[4] = {bbv[u].x, bbv[u].y, bbv[u].z, bbv[u].w};
#pragma unroll
            for (int e = 0; e < 4; ++e) {
                float l = lv[e], a = av[e], bb = bv[e];
                float va = (a + 1.f) * 0.5f;
                float vb = (bb + 1.f) * 0.5f;
                if (a != 0.f && bb != 0.f && va >= 0.f && va <= 1.f && vb >= 0.f && vb <= 1.f) {
                    int ia = min(max((int)floorf(va * 64.f), 0), 63);
                    int ib = min(max((int)floorf(vb * 64.f), 0), 63);
                    atomicAdd(&h2[ia * 64 + ib], 1u);
                }
                float vl = (l + 1.f) * 0.5f;
                if (l != 0.f && vl >= 0.f && vl <= 1.f) {
                    int il = min(max((int)floorf(vl * 8.f), 0), 7);
                    cL += 1ull << (il << 3);
                }
            }
        }
    }
    unsigned cc[8];
#pragma unroll
    for (int e = 0; e < 8; ++e) cc[e] = (unsigned)((cL >> (e << 3)) & 0xffull);
#pragma unroll
    for (int e = 0; e < 8; ++e) cc[e] = wred_u32(cc[e]);
    if ((tid & 63) == 0) {
        int w = tid >> 6;
#pragma unroll
        for (int e = 0; e < 8; ++e) wv[w][e] = cc[e];
    }
    __syncthreads();
    if (tid < 8) {
        unsigned s = 0;
#pragma unroll
        for (int w = 0; w < 8; ++w) s += wv[w][tid];
        cnt1p[((size_t)b * 16 + chunk) * 8 + tid] = s;
    }
    // partial writeout + block-sum (non-atomic, idempotent)
    uint4* pd = (uint4*)(part + (((size_t)b * 16 + chunk) << 12));
    const uint4* hs = (const uint4*)h2;
    unsigned mysum = 0;
    for (int i = tid; i < 1024; i += 512) {
        uint4 v = hs[i];
        pd[i] = v;
        mysum += v.x + v.y + v.z + v.w;
    }
    rsum[tid] = mysum;
    __syncthreads();
    for (int off = 256; off > 0; off >>= 1) {
        if (tid < off) rsum[tid] += rsum[tid + off];
        __syncthreads();
    }
    if (tid == 0) bsum[b * 16 + chunk] = rsum[0];
}

// ---------------- conv1 (+inline hist normalize) -> zt[b][37][35][128] fp8 (+halo zero) ------
__global__ __launch_bounds__(256) void conv1_pool(
    const unsigned* __restrict__ part, const unsigned* __restrict__ bsum,
    const unsigned* __restrict__ cnt1p,
    const float* __restrict__ w1, const float* __restrict__ g1,
    const float* __restrict__ b1v, const float* __restrict__ m1,
    const float* __restrict__ v1, unsigned char* __restrict__ zt)
{
    const int p = blockIdx.x;   // 0..32
    const int b = blockIdx.y;
    __shared__ float aL[128], cL[128], sL[128];
    __shared__ float Hrow[3][64];          // raw counts; scaled by inv2 at use
    __shared__ unsigned bs16[16];
    __shared__ float hlsh[8];
    __shared__ float qmx[33], qmn[33];
    __shared__ int qbd[33];
    const int tid = threadIdx.x;

    // phase 1: gather counts
    if (tid < 192) {
        int rr = tid >> 6, cc = tid & 63;
        int row = 2 * p - 2 + rr;
        float s = 0.f;
        if (row >= 0 && row < 64) {
            unsigned acc = 0;
#pragma unroll 1
            for (int k = 0; k < 16; ++k)
                acc += part[(((size_t)b * 16 + k) << 12) + (cc << 6) + row];  // bin = ia*64+ib, ia=cc, ib=row
            s = (float)acc;
        }
        Hrow[rr][cc] = s;
    } else if (tid < 208) {
        bs16[tid - 192] = bsum[b * 16 + (tid - 192)];
    } else if (tid < 216) {
        int c = tid - 208;
        unsigned s = 0;
#pragma unroll 1
        for (int k = 0; k < 16; ++k) s += cnt1p[((size_t)b * 16 + k) * 8 + c];
        hlsh[c] = (float)s;
    }
    __syncthreads();

    unsigned tt = 0;
#pragma unroll
    for (int i = 0; i < 16; ++i) tt += bs16[i];
    const float inv2 = 1.f / (float)tt;
    float hltot = 0.f;
#pragma unroll
    for (int c = 0; c < 8; ++c) hltot += hlsh[c];
    const float invl = 1.f / hltot;

    if (tid < 128) {
        int oc = tid;
        float inv = g1[oc] * rsqrtf(v1[oc] + 1e-5f);
        float s = b1v[oc] - m1[oc] * inv;
        float Kc = 0.f;
#pragma unroll
        for (int c = 1; c < 9; ++c) Kc = fmaf(w1[oc * 9 + c], hlsh[c - 1] * invl, Kc);
        aL[oc] = w1[oc * 9] * inv;
        cL[oc] = fmaf(Kc, inv, s);
        sL[oc] = s;
    }
    if (tid >= 128 && tid < 161) {
        int q = tid - 128;
        float mx = -1e30f, mn = 1e30f;
        int bd = 0;
#pragma unroll
        for (int dy = 0; dy < 3; ++dy) {
            int yi = 2 * p - 1 + dy;
            if (yi < 0 || yi > 65) continue;
#pragma unroll
            for (int dx = 0; dx < 3; ++dx) {
                int yj = 2 * q - 1 + dx;
                if (yj < 0 || yj > 65) continue;
                if (yi == 0 || yi == 65 || yj == 0 || yj == 65) bd = 1;
                else {
                    float h = Hrow[dy][2 * q - 2 + dx];
                    mx = fmaxf(mx, h); mn = fminf(mn, h);
                }
            }
        }
        qmx[q] = mx * inv2; qmn[q] = mn * inv2; qbd[q] = bd;
    }
    __syncthreads();
    unsigned char* zrow = zt + (((size_t)b * 37 + (p + 1)) * 35 + 1) * 128;
    for (int it = tid; it < 33 * 128; it += 256) {
        int q = it >> 7, oc = it & 127;
        float a = aL[oc];
        float v = fmaf(a, (a > 0.f ? qmx[q] : qmn[q]), cL[oc]);
        if (qbd[q]) v = fmaxf(v, sL[oc]);
        v = fmaxf(v, 0.f);
        zrow[q * 128 + oc] = f2e4m3(v);
    }
    // halo zeroing
    {
        int col = (tid < 128) ? 0 : 34;
        int ch = tid & 127;
        zt[(((size_t)b * 37 + (p + 1)) * 35 + col) * 128 + ch] = 0;
    }
    if (p < 4) {
        int hr = (p == 0) ? 0 : (33 + p);
        unsigned char* hrow = zt + ((size_t)b * 37 + hr) * 35 * 128;
        for (int i = tid; i < 35 * 128; i += 256) hrow[i] = 0;
    }
}

// ---------------- conv2: 9 tap-GEMMs, MX-fp8 K=128, single 32KB buffer, 3 blocks/CU ----------
__global__ __launch_bounds__(256, 3) void conv2_mfma(
        const unsigned char* __restrict__ zt,
        const unsigned char* __restrict__ w2r,
        const float* __restrict__ g2, const float* __restrict__ b2v,
        const float* __restrict__ m2, const float* __restrict__ v2,
        float* __restrict__ featp)
{
    __shared__ char lds[32768];   // A 16KB + B 16KB (single buffer; TLP hides staging)
    const int tid = threadIdx.x;
    const int lane = tid & 63, wid = tid >> 6;
    const int b = blockIdx.z;
    const int nbase = blockIdx.x * 128;
    const int mbase = blockIdx.y * 128;
    const int lr16 = lane & 15, lk = lane >> 4;
    const int wm = (wid >> 1) * 64, wn = (wid & 1) * 64;

    const int csrc = ((lane & 7) ^ (lane >> 3)) << 4;
    const unsigned char* aS[4];
    const unsigned char* bS[4];
    {
        const unsigned char* ztb = zt + (size_t)b * 165760;   // 37*35*128
#pragma unroll
        for (int v = 0; v < 4; ++v) {
            int R = wid * 32 + v * 8 + (lane >> 3);
            int m = mbase + R;
            int p = m / 33, q = m - p * 33;
            aS[v] = ztb + (p * 35 + q) * 128 + csrc;
            bS[v] = w2r + (size_t)(nbase + R) * 128 + csrc;
        }
    }

    f32x4 acc[4][4];
#pragma unroll
    for (int i = 0; i < 4; ++i)
#pragma unroll
        for (int j = 0; j < 4; ++j) acc[i][j] = (f32x4){0.f, 0.f, 0.f, 0.f};

    auto stage = [&](int tap) {
        const int kh = tap / 3, kw = tap - kh * 3;
        const int aoff = (kh * 35 + kw) * 128;
        const int boff = tap * 131072;
        char* ab = lds + wid * 4096;
        char* bb = lds + 16384 + wid * 4096;
#pragma unroll
        for (int v = 0; v < 4; ++v)
            __builtin_amdgcn_global_load_lds(
                (const __attribute__((address_space(1))) unsigned int*)(aS[v] + aoff),
                (__attribute__((address_space(3))) unsigned int*)(ab + v * 1024), 16, 0, 0);
#pragma unroll
        for (int v = 0; v < 4; ++v)
            __builtin_amdgcn_global_load_lds(
                (const __attribute__((address_space(1))) unsigned int*)(bS[v] + boff),
                (__attribute__((address_space(3))) unsigned int*)(bb + v * 1024), 16, 0, 0);
    };

    auto compute = [&]() {
        const char* Ab = lds;
        const char* Bb = lds + 16384;
        i32x8 af[4], bf[4];
#pragma unroll
        for (int i = 0; i < 4; ++i) {
            int row = wm + i * 16 + lr16;
            const char* base = Ab + row * 128;
            int x = row & 7;
            int4 lo = *(const int4*)(base + (((2 * lk) ^ x) << 4));
            int4 hi = *(const int4*)(base + (((2 * lk + 1) ^ x) << 4));
            af[i] = (i32x8){lo.x, lo.y, lo.z, lo.w, hi.x, hi.y, hi.z, hi.w};
        }
#pragma unroll
        for (int j = 0; j < 4; ++j) {
            int row = wn + j * 16 + lr16;
            const char* base = Bb + row * 128;
            int x = row & 7;
            int4 lo = *(const int4*)(base + (((2 * lk) ^ x) << 4));
            int4 hi = *(const int4*)(base + (((2 * lk + 1) ^ x) << 4));
            bf[j] = (i32x8){lo.x, lo.y, lo.z, lo.w, hi.x, hi.y, hi.z, hi.w};
        }
#pragma unroll
        for (int i = 0; i < 4; ++i)
#pragma unroll
            for (int j = 0; j < 4; ++j)
                acc[i][j] = __builtin_amdgcn_mfma_scale_f32_16x16x128_f8f6f4(
                    af[i], bf[j], acc[i][j],
                    0, 0, 0, 0x7F7F7F7F, 0, 0x7F7F7F7F);
    };

#pragma unroll 1
    for (int t = 0; t < 9; ++t) {
        stage(t);
        asm volatile("s_waitcnt vmcnt(0)" ::: "memory");
        __syncthreads();
        compute();
        __syncthreads();
    }

    // epilogue: BN2 + ReLU + masked column sums -> featp
    float* red = (float*)lds;
#pragma unroll
    for (int j = 0; j < 4; ++j) {
        int nl = wn + j * 16 + lr16;
        int n = nbase + nl;
        float inv = g2[n] * rsqrtf(v2[n] + 1e-5f);
        float sh = b2v[n] - m2[n] * inv;
        float ssum = 0.f;
#pragma unroll
        for (int i = 0; i < 4; ++i) {
            int mlb = wm + i * 16 + lk * 4;
#pragma unroll
            for (int r = 0; r < 4; ++r) {
                if (mbase + mlb + r < M_SP)
                    ssum += fmaxf(fmaf(acc[i][j][r], inv, sh), 0.f);
            }
        }
        red[((wid >> 1) * 4 + lk) * 128 + nl] = ssum;
    }
    __syncthreads();
    if (tid < 128) {
        float s = 0.f;
#pragma unroll
        for (int c = 0; c < 8; ++c) s += red[c * 128 + tid];
        featp[blockIdx.y * 16384 + b * 1024 + nbase + tid] = s * (1.f / 1089.f);
    }
}

// ---------------- head: fused x-copy + feature-sum + linear ----------------
__global__ __launch_bounds__(256) void linear_head(const float* __restrict__ featp,
                                                   const float* __restrict__ x,
                                                   const float* __restrict__ wl,
                                                   const float* __restrict__ bl,
                                                   float* __restrict__ out) {
    int jg = blockIdx.x, b = blockIdx.y;   // grid (16,16)
    __shared__ float fsum[1024];
    int tid = threadIdx.x;
    if (tid < 128)
        out[b * 2304 + jg * 128 + tid] = x[b * 2048 + jg * 128 + tid];
    for (int c = tid; c < 1024; c += 256) {
        float s = 0.f;
#pragma unroll
        for (int mb = 0; mb < 9; ++mb) s += featp[mb * 16384 + b * 1024 + c];
        fsum[c] = s;
    }
    __syncthreads();
    int w = tid >> 6, lane = tid & 63;
#pragma unroll
    for (int jj = 0; jj < 4; ++jj) {
        int j = jg * 16 + w * 4 + jj;
        const float* wr = wl + j * 1024;
        float s = 0.f;
        for (int k = lane; k < 1024; k += 64) s = fmaf(fsum[k], wr[k], s);
#pragma unroll
        for (int off = 32; off > 0; off >>= 1) s += __shfl_down(s, off);
        if (lane == 0) out[b * 2304 + 2048 + j] = s + bl[j];
    }
}

extern "C" void kernel_launch(void* const* d_in, const int* in_sizes, int n_in,
                              void* d_out, int out_size, void* d_ws, size_t ws_size,
                              hipStream_t stream) {
    const float* x  = (const float*)d_in[0];
    const float* x1 = (const float*)d_in[1];
    const float* w1 = (const float*)d_in[2];
    const float* g1 = (const float*)d_in[3];
    const float* b1 = (const float*)d_in[4];
    const float* m1 = (const float*)d_in[5];
    const float* v1 = (const float*)d_in[6];
    const float* w2 = (const float*)d_in[7];
    const float* g2 = (const float*)d_in[8];
    const float* b2 = (const float*)d_in[9];
    const float* m2 = (const float*)d_in[10];
    const float* v2 = (const float*)d_in[11];
    const float* wl = (const float*)d_in[12];
    const float* bl = (const float*)d_in[13];
    float* out = (float*)d_out;

    float* wsf = (float*)d_ws;
    unsigned* part  = (unsigned*)(wsf + OFF_PART);
    unsigned* bsum  = (unsigned*)(wsf + OFF_BSUM);
    unsigned* cnt1p = (unsigned*)(wsf + OFF_CNT1P);
    unsigned char* w2r = (unsigned char*)(wsf + OFF_W2R);
    unsigned char* zt  = (unsigned char*)(wsf + OFF_ZT);
    float* featp = wsf + OFF_FEATP;

    prep_kernel<<<512, 512, 0, stream>>>(x1, w2, part, bsum, cnt1p, w2r);
    conv1_pool<<<dim3(33, 16), 256, 0, stream>>>(part, bsum, cnt1p, w1, g1, b1, m1, v1, zt);
    conv2_mfma<<<dim3(8, 9, 16), 256, 0, stream>>>(zt, w2r, g2, b2, m2, v2, featp);
    linear_head<<<dim3(16, 16), 256, 0, stream>>>(featp, x, wl, bl, out);
}